// Round 7
// baseline (143.307 us; speedup 1.0000x reference)
//
#include <hip/hip_runtime.h>
#include <hip/hip_bf16.h>

// Attention_69277822485182: paged GQA diffusion-block attention, fp32 in/out.
// S=8, H=32, H_KV=8 (G=4), D=128, Q=64, CTX=2048 -> 66 kv tiles of 32, no mask.
//
// Round 7: TLP. grid 256 = (s,hkv) x 4 kv-slices; block = 1024 thr / 16 waves
//  = 2 in-block kv-halves x 4 g x 2 q-halves -> 4 waves/SIMD (vs 2 in R6).
//  Each half: own K/V dbuf, single-barrier rotation
//  {barrier; write(t+1); load(t+2); compute(t)} (R4-verified). In-block
//  2-way merge via 64KB LDS overlay (2 g-pair rounds), slice partials -> ws,
//  combine kernel (unchanged from R6) sums 4 slices + divides.
//  Kept verified pieces: 32x32x16 swapped QK^T (lane-local no-max exp2
//  softmax), K/V/P conflict-free swizzles, GQA-fused staging, setprio on MFMA.
// The reference's kv-cache scatter writes blocks never referenced by
// block_tables, so only the attention output is produced.

typedef float  f32x16 __attribute__((ext_vector_type(16)));
typedef short  bf16x8 __attribute__((ext_vector_type(8)));

__device__ __forceinline__ unsigned pkbf(float lo, float hi) {
    union { __hip_bfloat162 h; unsigned u; } t;
    t.h.x = __float2bfloat16(lo);
    t.h.y = __float2bfloat16(hi);
    return t.u;
}

// ws layout: Ows [4][64][256][128] f32 (33.55 MB), then Lws [4][64][256] f32.
#define LWS_OFF (4u * 64u * 256u * 128u)

__launch_bounds__(1024, 4)
__global__ void attn_part(const float* __restrict__ qg,
                          const float* __restrict__ kin,
                          const float* __restrict__ vin,
                          const float* __restrict__ kcache,
                          const float* __restrict__ vcache,
                          const int*   __restrict__ bt,
                          float* __restrict__ Ows,
                          float* __restrict__ Lws)
{
    // half h: K dbuf 2x8KB @ h*32768, V^T dbuf 2x8KB @ h*32768+16384
    // P: @65536 + w*2048.  Total 96KB.
    __shared__ __align__(16) unsigned char smem[98304];

    const int bid   = blockIdx.x;
    const int grp   = bid & 63;        // (s,hkv)
    const int slice = bid >> 6;        // kv slice 0..3
    const int s     = grp >> 3;
    const int hkv   = grp & 7;

    const int tid    = threadIdx.x;
    const int w      = tid >> 6;       // 0..15
    const int kvhalf = w >> 3;         // in-block kv half
    const int wg     = w & 7;          // 0..7 = g*2 + qh
    const int g      = wg >> 1;
    const int qh     = wg & 1;
    const int lane   = tid & 63;
    const int l32    = lane & 31;
    const int hi2    = lane >> 5;
    const int qtid   = tid & 511;      // staging id within half

    unsigned char* KB = smem + kvhalf * 32768;
    unsigned char* VB = smem + kvhalf * 32768 + 16384;
    unsigned char* PB = smem + 65536 + w * 2048;

    const float QSCALE = 0.08838834764831845f * 1.44269504088896340736f;

    // ---- Q -> registers (B-frag of swapped QK): Q[q=l32][d = dc*16 + hi2*8 + j]
    bf16x8 aq[8];
    {
        const float* qp =
            qg + (size_t)((s * 64 + qh * 32 + l32) * 32 + hkv * 4 + g) * 128;
#pragma unroll
        for (int dc = 0; dc < 8; ++dc) {
            const float* p = qp + dc * 16 + hi2 * 8;
            const float4 f0 = *(const float4*)(p);
            const float4 f1 = *(const float4*)(p + 4);
            uint4 tt = make_uint4(pkbf(f0.x * QSCALE, f0.y * QSCALE),
                                  pkbf(f0.z * QSCALE, f0.w * QSCALE),
                                  pkbf(f1.x * QSCALE, f1.y * QSCALE),
                                  pkbf(f1.z * QSCALE, f1.w * QSCALE));
            aq[dc] = __builtin_bit_cast(bf16x8, tt);
        }
    }

    f32x16 acco[4];
#pragma unroll
    for (int dc = 0; dc < 4; ++dc) acco[dc] = (f32x16)0.f;
    float lsum = 0.f;

    // staging: K via 2 float4/thread; V via 8 scalars/thread (d along lanes)
    const int vd  = qtid & 127;        // V: d row
    const int vkg = qtid >> 7;         // V: kv group -> 16B unit

    float4 kreg[2];
    float  vreg[8];

    // slice tiles, then split across the two in-block halves
    const int slice_t0 = (slice < 2) ? slice * 17 : 34 + (slice - 2) * 16;
    const int slice_nt = (slice < 2) ? 17 : 16;
    const int nh0      = (slice_nt + 1) >> 1;                // 9 or 8
    const int t0       = slice_t0 + kvhalf * nh0;
    const int nt       = kvhalf ? (slice_nt - nh0) : nh0;    // 8 or 9

    auto load_regs = [&](int T) {
        const float *ks, *vs;
        if (T < 64) {
            const int blk = bt[s * 32 + (T >> 1)];
            const size_t base = (size_t)blk * 65536 + (size_t)(T & 1) * 32768 + hkv * 128;
            ks = kcache + base; vs = vcache + base;
        } else {
            const size_t base = (size_t)(s * 64 + (T & 1) * 32) * 1024 + hkv * 128;
            ks = kin + base; vs = vin + base;
        }
#pragma unroll
        for (int i = 0; i < 2; ++i) {
            const int f = qtid + 512 * i;
            kreg[i] = *(const float4*)(ks + (size_t)(f >> 5) * 1024 + (f & 31) * 4);
        }
#pragma unroll
        for (int j = 0; j < 8; ++j)
            vreg[j] = vs[(size_t)(vkg * 8 + j) * 1024 + vd];
    };

    auto write_lds = [&](int buf) {
        unsigned char* K = KB + buf * 8192;
        unsigned char* V = VB + buf * 8192;
#pragma unroll
        for (int i = 0; i < 2; ++i) {
            const int f  = qtid + 512 * i;
            const int kv = f >> 5;
            const int dk = f & 31;                  // 8B unit in 256B row
            const int Xs = dk ^ ((kv & 15) << 1);
            *(uint2*)(K + kv * 256 + Xs * 8) =
                make_uint2(pkbf(kreg[i].x, kreg[i].y), pkbf(kreg[i].z, kreg[i].w));
        }
        const int u = vkg ^ ((vd >> 1) & 3);        // V^T row vd: 64B, 4x16B units
        *(uint4*)(V + vd * 64 + u * 16) =
            make_uint4(pkbf(vreg[0], vreg[1]), pkbf(vreg[2], vreg[3]),
                       pkbf(vreg[4], vreg[5]), pkbf(vreg[6], vreg[7]));
    };

    const int vq = (l32 >> 1) & 3;     // P/V read swizzle for this lane

    auto compute = [&](int buf) {
        const unsigned char* K = KB + buf * 8192;
        const unsigned char* V = VB + buf * 8192;

        // swapped QK^T: C[kv][q], col q = l32
        f32x16 sc = (f32x16)0.f;
        __builtin_amdgcn_s_setprio(1);
#pragma unroll
        for (int dc = 0; dc < 8; ++dc) {
            const int u = (dc * 2 + hi2) ^ (l32 & 15);
            const bf16x8 ak = *(const bf16x8*)(K + l32 * 256 + u * 16);
            sc = __builtin_amdgcn_mfma_f32_32x32x16_bf16(ak, aq[dc], sc, 0, 0, 0);
        }
        __builtin_amdgcn_s_setprio(0);

        // lane-local no-max softmax (rows kv = (r&3) + 8*(r>>2) + 4*hi2)
        float p[16];
#pragma unroll
        for (int r = 0; r < 16; ++r) {
            p[r] = __builtin_amdgcn_exp2f(sc[r]);
            lsum += p[r];
        }

        // P -> per-wave LDS [q rows of 64B], block-XOR swizzle
#pragma unroll
        for (int rq = 0; rq < 4; ++rq)
#pragma unroll
            for (int e = 0; e < 2; ++e)
                *(unsigned*)(PB + l32 * 64 + ((rq ^ vq) * 16) + (2 * hi2 + e) * 4) =
                    pkbf(p[rq * 4 + 2 * e], p[rq * 4 + 2 * e + 1]);
        asm volatile("s_waitcnt lgkmcnt(0)" ::: "memory"); // wave-private buffer

        bf16x8 pa[2];
#pragma unroll
        for (int kk = 0; kk < 2; ++kk)
            pa[kk] = *(const bf16x8*)(PB + l32 * 64 + (((kk * 2 + hi2) ^ vq) * 16));

        // PV: C[q][d] per 32-d block
        __builtin_amdgcn_s_setprio(1);
#pragma unroll
        for (int kk = 0; kk < 2; ++kk)
#pragma unroll
            for (int d2 = 0; d2 < 4; ++d2) {
                const int u = (kk * 2 + hi2) ^ vq;
                const bf16x8 bv = *(const bf16x8*)(V + (d2 * 32 + l32) * 64 + u * 16);
                acco[d2] = __builtin_amdgcn_mfma_f32_32x32x16_bf16(pa[kk], bv, acco[d2], 0, 0, 0);
            }
        __builtin_amdgcn_s_setprio(0);
    };

    // ---- prologue + main loop: ONE barrier per step, uniform 9 iterations
    load_regs(t0);
    write_lds(0);
    load_regs(t0 + 1);

    for (int tt = 0; tt < 9; ++tt) {
        __syncthreads();
        if (tt + 1 < nt) write_lds((tt + 1) & 1);
        if (tt + 2 < nt) load_regs(t0 + tt + 2);
        if (tt < nt)     compute(tt & 1);
    }

    // ---- in-block merge of the two kv-halves (2 g-pair rounds, 64KB overlay)
    float lt = lsum + __shfl_xor(lsum, 32);   // full kv-sum for q-col l32

    float* OC = (float*)smem;                 // [128 q][128 d] chunk
    float* LC = (float*)(smem + 65536);       // [128] l-sums (P region, dead)

    const int qcbase = (g & 1) * 64 + qh * 32;    // q-row base within chunk

#pragma unroll
    for (int rr = 0; rr < 2; ++rr) {
        __syncthreads();
        if (kvhalf == 1 && (g >> 1) == rr) {
#pragma unroll
            for (int dc = 0; dc < 4; ++dc)
#pragma unroll
                for (int r = 0; r < 16; ++r) {
                    const int row = (r & 3) + 8 * (r >> 2) + 4 * hi2;
                    OC[(qcbase + row) * 128 + dc * 32 + l32] = acco[dc][r];
                }
            if (hi2 == 0) LC[qcbase + l32] = lt;
        }
        __syncthreads();
        if (kvhalf == 0 && (g >> 1) == rr) {
#pragma unroll
            for (int dc = 0; dc < 4; ++dc)
#pragma unroll
                for (int r = 0; r < 16; ++r) {
                    const int row = (r & 3) + 8 * (r >> 2) + 4 * hi2;
                    acco[dc][r] += OC[(qcbase + row) * 128 + dc * 32 + l32];
                }
            lt += LC[qcbase + l32];
        }
    }

    // ---- epilogue: slice partials -> workspace (kvhalf0 waves only)
    if (kvhalf == 0) {
        const size_t gq = (size_t)(slice * 64 + grp) * 256 + wg * 32;
        if (hi2 == 0) Lws[gq + l32] = lt;
        float* Od = Ows + gq * 128;
#pragma unroll
        for (int dc = 0; dc < 4; ++dc)
#pragma unroll
            for (int r = 0; r < 16; ++r) {
                const int qiw = (r & 3) + 8 * (r >> 2) + 4 * hi2;
                Od[(size_t)qiw * 128 + dc * 32 + l32] = acco[dc][r];
            }
    }
}

__launch_bounds__(256)
__global__ void attn_combine(const float* __restrict__ Ows,
                             const float* __restrict__ Lws,
                             float* __restrict__ out)
{
    const int idx = blockIdx.x * 256 + threadIdx.x;  // 0..524287
    const int dq  = idx & 31;                        // float4 within d=128
    const int qr  = (idx >> 5) & 255;                // q-row in group (g*64+qtok)
    const int grp = idx >> 13;                       // 0..63
    const int s = grp >> 3, hkv = grp & 7;
    const int g = qr >> 6, qtok = qr & 63;

    float4 acc = make_float4(0.f, 0.f, 0.f, 0.f);
    float  l   = 0.f;
#pragma unroll
    for (int sl = 0; sl < 4; ++sl) {
        const size_t base = (size_t)(sl * 64 + grp) * 256 + qr;
        const float4 p = *(const float4*)(Ows + base * 128 + dq * 4);
        acc.x += p.x; acc.y += p.y; acc.z += p.z; acc.w += p.w;
        l += Lws[base];
    }
    const float inv = 1.0f / l;
    float4 o = make_float4(acc.x * inv, acc.y * inv, acc.z * inv, acc.w * inv);
    *(float4*)(out + ((size_t)((s * 64 + qtok) * 32 + hkv * 4 + g)) * 128 + dq * 4) = o;
}

extern "C" void kernel_launch(void* const* d_in, const int* in_sizes, int n_in,
                              void* d_out, int out_size, void* d_ws, size_t ws_size,
                              hipStream_t stream)
{
    const float* q  = (const float*)d_in[0];
    const float* k  = (const float*)d_in[1];
    const float* v  = (const float*)d_in[2];
    const float* kc = (const float*)d_in[3];
    const float* vc = (const float*)d_in[4];
    const int*   bt = (const int*)d_in[5];
    float* Ows = (float*)d_ws;
    float* Lws = Ows + LWS_OFF;
    float* o   = (float*)d_out;

    attn_part<<<dim3(256), dim3(1024), 0, stream>>>(q, k, v, kc, vc, bt, Ows, Lws);
    attn_combine<<<dim3(2048), dim3(256), 0, stream>>>(Ows, Lws, o);
}

// Round 8
// 52.581 us; speedup vs baseline: 2.7255x; 2.7255x over previous
//
#include <hip/hip_runtime.h>
#include <hip/hip_bf16.h>

// Attention_69277822485182: paged GQA diffusion-block attention, fp32 in/out.
// S=8, H=32, H_KV=8 (G=4), D=128, Q=64, CTX=2048 -> 66 kv tiles of 32, no mask.
//
// Round 8: register-safe TLP.
//  - launch_bounds 2nd arg behaves as blocks/CU on this stack (R6/R7 evidence):
//    (512,2) -> VGPR cap 128 (proven). R7's (1024,4) -> cap 64 -> spill disaster.
//  - mfma_16x16x32, 16 q-rows/wave: acco 32 + aq 16 + staging 16 regs -> ~95
//    natural VGPR, no spill at cap 128.
//  - grid 512 = (qhalf 2) x (kv-slice 4) x (s,hkv 64); block 512 thr / 8 waves
//    = 4 g x 2 q-subtiles (GQA-fused staging; no in-block kv split/merge)
//    -> 2 blocks/CU, 4 waves/SIMD. qhalf siblings == mod 8 -> same XCD L2.
//  - kept verified: single-barrier dbuf rotation {barrier; write(t+1);
//    load(t+2); compute(t)}, swapped QK^T (lane-local no-max exp2 softmax),
//    K/V swizzles (R5/R6), ws partials + combine kernel (R6).
//  - P per-wave 1KB LDS, block-XOR swizzle (^(l16&3) on 16B blocks).
// The reference's kv-cache scatter writes blocks never referenced by
// block_tables, so only the attention output is produced.

typedef float  f32x4  __attribute__((ext_vector_type(4)));
typedef short  bf16x8 __attribute__((ext_vector_type(8)));

__device__ __forceinline__ unsigned pkbf(float lo, float hi) {
    union { __hip_bfloat162 h; unsigned u; } t;
    t.h.x = __float2bfloat16(lo);
    t.h.y = __float2bfloat16(hi);
    return t.u;
}

// ws layout: Ows [4][64][256][128] f32 (33.55 MB), then Lws [4][64][256] f32.
#define LWS_OFF (4u * 64u * 256u * 128u)

__launch_bounds__(512, 2)
__global__ void attn_part(const float* __restrict__ qg,
                          const float* __restrict__ kin,
                          const float* __restrict__ vin,
                          const float* __restrict__ kcache,
                          const float* __restrict__ vcache,
                          const int*   __restrict__ bt,
                          float* __restrict__ Ows,
                          float* __restrict__ Lws)
{
    // K dbuf 2x8KB @0, V^T dbuf 2x8KB @16384, P 8x1KB @32768 -> 40KB
    __shared__ __align__(16) unsigned char smem[40960];

    const int bid   = blockIdx.x;
    const int qhalf = bid >> 8;        // q-token half [32*qhalf, 32*qhalf+32)
    const int slice = (bid >> 6) & 3;  // kv slice
    const int grp   = bid & 63;        // (s,hkv); qhalf siblings == mod 8 -> same XCD
    const int s     = grp >> 3;
    const int hkv   = grp & 7;

    const int tid  = threadIdx.x;
    const int w    = tid >> 6;         // 0..7
    const int g    = w >> 1;           // GQA sub-head
    const int qsub = w & 1;            // 16-row q subtile within the half
    const int lane = tid & 63;
    const int l16  = lane & 15;
    const int hi4  = lane >> 4;

    unsigned char* KB = smem;
    unsigned char* VB = smem + 16384;
    unsigned char* PB = smem + 32768 + w * 1024;

    const float QSCALE = 0.08838834764831845f * 1.44269504088896340736f;

    // ---- Q -> registers (B-frag of swapped QK): lane: Q[q=l16][d=dc*32+hi4*8+j]
    bf16x8 aq[4];
    {
        const float* qp = qg +
            (size_t)((s * 64 + qhalf * 32 + qsub * 16 + l16) * 32 + hkv * 4 + g) * 128;
#pragma unroll
        for (int dc = 0; dc < 4; ++dc) {
            const float* p = qp + dc * 32 + hi4 * 8;
            const float4 f0 = *(const float4*)(p);
            const float4 f1 = *(const float4*)(p + 4);
            uint4 tt = make_uint4(pkbf(f0.x * QSCALE, f0.y * QSCALE),
                                  pkbf(f0.z * QSCALE, f0.w * QSCALE),
                                  pkbf(f1.x * QSCALE, f1.y * QSCALE),
                                  pkbf(f1.z * QSCALE, f1.w * QSCALE));
            aq[dc] = __builtin_bit_cast(bf16x8, tt);
        }
    }

    f32x4 acco[8];                     // O[q=4hi4+r][d=db*16+l16]
#pragma unroll
    for (int db = 0; db < 8; ++db) acco[db] = (f32x4){0.f, 0.f, 0.f, 0.f};
    float lsum = 0.f;

    // staging: K 2x float4/thread, V 8 scalars/thread (d along lanes)
    const int vd  = tid & 127;
    const int vkg = tid >> 7;          // 0..3 -> kv group of 8

    float4 kreg[2];
    float  vreg[8];

    const int tile0 = (slice < 2) ? slice * 17 : 34 + (slice - 2) * 16;
    const int nt    = (slice < 2) ? 17 : 16;

    auto load_regs = [&](int T) {
        const float *ks, *vs;
        if (T < 64) {
            const int blk = bt[s * 32 + (T >> 1)];
            const size_t base = (size_t)blk * 65536 + (size_t)(T & 1) * 32768 + hkv * 128;
            ks = kcache + base; vs = vcache + base;
        } else {
            const size_t base = (size_t)(s * 64 + (T & 1) * 32) * 1024 + hkv * 128;
            ks = kin + base; vs = vin + base;
        }
#pragma unroll
        for (int i = 0; i < 2; ++i) {
            const int f = tid + 512 * i;
            kreg[i] = *(const float4*)(ks + (size_t)(f >> 5) * 1024 + (f & 31) * 4);
        }
#pragma unroll
        for (int j = 0; j < 8; ++j)
            vreg[j] = vs[(size_t)(vkg * 8 + j) * 1024 + vd];
    };

    auto write_lds = [&](int buf) {
        unsigned char* K = KB + buf * 8192;
        unsigned char* V = VB + buf * 8192;
#pragma unroll
        for (int i = 0; i < 2; ++i) {
            const int f  = tid + 512 * i;
            const int kv = f >> 5;
            const int dk = f & 31;                  // 8B unit in 256B row
            const int Xs = dk ^ ((kv & 15) << 1);
            *(uint2*)(K + kv * 256 + Xs * 8) =
                make_uint2(pkbf(kreg[i].x, kreg[i].y), pkbf(kreg[i].z, kreg[i].w));
        }
        const int u = vkg ^ ((vd >> 1) & 3);        // V^T row vd: 64B, 4x16B units
        *(uint4*)(V + vd * 64 + u * 16) =
            make_uint4(pkbf(vreg[0], vreg[1]), pkbf(vreg[2], vreg[3]),
                       pkbf(vreg[4], vreg[5]), pkbf(vreg[6], vreg[7]));
    };

    const int pswz = l16 & 3;          // P block swizzle
    const int vswz = (l16 >> 1) & 3;   // V read swizzle

    auto compute = [&](int buf) {
        const unsigned char* K = KB + buf * 8192;
        const unsigned char* V = VB + buf * 8192;

        // ---- swapped QK^T: C[kv][q], col q = l16, 2 kv row-blocks
        f32x4 sc[2];
#pragma unroll
        for (int ct = 0; ct < 2; ++ct) sc[ct] = (f32x4){0.f, 0.f, 0.f, 0.f};
        __builtin_amdgcn_s_setprio(1);
#pragma unroll
        for (int dc = 0; dc < 4; ++dc) {
            const int u = (dc * 4 + hi4) ^ l16;
#pragma unroll
            for (int ct = 0; ct < 2; ++ct) {
                const bf16x8 ak = *(const bf16x8*)(K + (ct * 16 + l16) * 256 + u * 16);
                sc[ct] = __builtin_amdgcn_mfma_f32_16x16x32_bf16(ak, aq[dc], sc[ct], 0, 0, 0);
            }
        }
        __builtin_amdgcn_s_setprio(0);

        // ---- lane-local no-max softmax (kv = ct*16 + 4*hi4 + r) + P write
#pragma unroll
        for (int ct = 0; ct < 2; ++ct) {
            const float p0 = __builtin_amdgcn_exp2f(sc[ct][0]);
            const float p1 = __builtin_amdgcn_exp2f(sc[ct][1]);
            const float p2 = __builtin_amdgcn_exp2f(sc[ct][2]);
            const float p3 = __builtin_amdgcn_exp2f(sc[ct][3]);
            lsum += (p0 + p1) + (p2 + p3);
            // u32 unit U = ct*8 + 2*hi4 + e -> kv pair (2U, 2U+1); block = U>>2
            const int blkbase = ct * 2 + (hi4 >> 1);
            const int pos     = 2 * (hi4 & 1);
            unsigned char* prow = PB + l16 * 64 + ((blkbase ^ pswz) * 16);
            *(unsigned*)(prow + pos * 4)       = pkbf(p0, p1);
            *(unsigned*)(prow + (pos + 1) * 4) = pkbf(p2, p3);
        }
        asm volatile("s_waitcnt lgkmcnt(0)" ::: "memory"); // wave-private buffer

        // ---- P read as A-frag: lane needs kv = 8*hi4 + j  (natural block hi4)
        const bf16x8 pa = *(const bf16x8*)(PB + l16 * 64 + ((hi4 ^ pswz) * 16));

        // ---- PV: one mfma per 16-d block
        __builtin_amdgcn_s_setprio(1);
#pragma unroll
        for (int db = 0; db < 8; ++db) {
            const bf16x8 bv = *(const bf16x8*)(V + (db * 16 + l16) * 64 + ((hi4 ^ vswz) * 16));
            acco[db] = __builtin_amdgcn_mfma_f32_16x16x32_bf16(pa, bv, acco[db], 0, 0, 0);
        }
        __builtin_amdgcn_s_setprio(0);
    };

    // ---- prologue + main loop: ONE barrier per tile
    load_regs(tile0);
    write_lds(0);
    load_regs(tile0 + 1);

    for (int tt = 0; tt < nt; ++tt) {
        __syncthreads();
        if (tt + 1 < nt) write_lds((tt + 1) & 1);
        if (tt + 2 < nt) load_regs(tile0 + tt + 2);
        compute(tt & 1);
    }

    // ---- epilogue: slice partials -> workspace
    float lt = lsum;
    lt += __shfl_xor(lt, 16);
    lt += __shfl_xor(lt, 32);          // full 32-kv sum for q = l16

    const size_t gqbase = (size_t)(slice * 64 + grp) * 256
                        + g * 64 + qhalf * 32 + qsub * 16;
    if (hi4 == 0) Lws[gqbase + l16] = lt;
    float* Od = Ows + gqbase * 128;
#pragma unroll
    for (int db = 0; db < 8; ++db)
#pragma unroll
        for (int r = 0; r < 4; ++r)
            Od[(size_t)(4 * hi4 + r) * 128 + db * 16 + l16] = acco[db][r];
}

__launch_bounds__(256)
__global__ void attn_combine(const float* __restrict__ Ows,
                             const float* __restrict__ Lws,
                             float* __restrict__ out)
{
    const int idx = blockIdx.x * 256 + threadIdx.x;  // 0..524287
    const int dq  = idx & 31;                        // float4 within d=128
    const int qr  = (idx >> 5) & 255;                // q-row in group (g*64+qtok)
    const int grp = idx >> 13;                       // 0..63
    const int s = grp >> 3, hkv = grp & 7;
    const int g = qr >> 6, qtok = qr & 63;

    float4 acc = make_float4(0.f, 0.f, 0.f, 0.f);
    float  l   = 0.f;
#pragma unroll
    for (int sl = 0; sl < 4; ++sl) {
        const size_t base = (size_t)(sl * 64 + grp) * 256 + qr;
        const float4 p = *(const float4*)(Ows + base * 128 + dq * 4);
        acc.x += p.x; acc.y += p.y; acc.z += p.z; acc.w += p.w;
        l += Lws[base];
    }
    const float inv = 1.0f / l;
    float4 o = make_float4(acc.x * inv, acc.y * inv, acc.z * inv, acc.w * inv);
    *(float4*)(out + ((size_t)((s * 64 + qtok) * 32 + hkv * 4 + g)) * 128 + dq * 4) = o;
}

extern "C" void kernel_launch(void* const* d_in, const int* in_sizes, int n_in,
                              void* d_out, int out_size, void* d_ws, size_t ws_size,
                              hipStream_t stream)
{
    const float* q  = (const float*)d_in[0];
    const float* k  = (const float*)d_in[1];
    const float* v  = (const float*)d_in[2];
    const float* kc = (const float*)d_in[3];
    const float* vc = (const float*)d_in[4];
    const int*   bt = (const int*)d_in[5];
    float* Ows = (float*)d_ws;
    float* Lws = Ows + LWS_OFF;
    float* o   = (float*)d_out;

    attn_part<<<dim3(512), dim3(512), 0, stream>>>(q, k, v, kc, vc, bt, Ows, Lws);
    attn_combine<<<dim3(2048), dim3(256), 0, stream>>>(Ows, Lws, o);
}

// Round 9
// 51.808 us; speedup vs baseline: 2.7661x; 1.0149x over previous
//
#include <hip/hip_runtime.h>
#include <hip/hip_bf16.h>

// Attention_69277822485182: paged GQA diffusion-block attention, fp32 in/out.
// S=8, H=32, H_KV=8 (G=4), D=128, Q=64, CTX=2048 -> 66 kv tiles of 32, no mask.
//
// Round 9: R6 structure (best so far), grid-limited fix.
//  - 8 kv-slices (grid 512 = 64 grp x 8 slices, 8-9 tiles each) -> 2 blocks/CU
//    = 4 waves/SIMD. KV slices disjoint -> no traffic duplication (R8's error).
//    Resources checked: 48KB LDS x2 = 96KB <= 160KB; VGPR 128 x 16 waves =
//    2048/SIMD pool -> fits exactly. launch_bounds(512,2) proven cap-128.
//  - bf16 ws O-partials (16.8MB) keep combine ~7us at 8 slices; L stays f32.
//  - kept verified: GQA-fused block (8 waves = 4g x 2 q-halves, 256 q-rows
//    share each staged tile), single-barrier dbuf rotation {barrier;
//    write(t+1); load(t+2); compute(t)}, 32x32x16 swapped QK^T (lane-local
//    no-max exp2 softmax), K/V/P conflict-free swizzles, setprio on MFMA.
// The reference's kv-cache scatter writes blocks never referenced by
// block_tables, so only the attention output is produced.

typedef float  f32x16 __attribute__((ext_vector_type(16)));
typedef short  bf16x8 __attribute__((ext_vector_type(8)));

__device__ __forceinline__ unsigned pkbf(float lo, float hi) {
    union { __hip_bfloat162 h; unsigned u; } t;
    t.h.x = __float2bfloat16(lo);
    t.h.y = __float2bfloat16(hi);
    return t.u;
}
__device__ __forceinline__ float bf2f(unsigned short u) {
    return __uint_as_float((unsigned)u << 16);
}

// ws layout: Ows [8][64][256][128] bf16 (33.6M elems? no: 16.8M elems, 33.5MB->
// actually 8*64*256*128 = 16,777,216 bf16 = 33.55MB), then Lws [8][64][256] f32.
#define OWS_ELEMS (8u * 64u * 256u * 128u)

__launch_bounds__(512, 2)
__global__ void attn_part(const float* __restrict__ qg,
                          const float* __restrict__ kin,
                          const float* __restrict__ vin,
                          const float* __restrict__ kcache,
                          const float* __restrict__ vcache,
                          const int*   __restrict__ bt,
                          __hip_bfloat16* __restrict__ Ows,
                          float* __restrict__ Lws)
{
    // K dbuf 2x8KB @0, V^T dbuf 2x8KB @16384, P 8x2KB @32768 -> 48KB
    __shared__ __align__(16) unsigned char smem[49152];

    const int bid   = blockIdx.x;
    const int grp   = bid & 63;        // (s,hkv); slice siblings == mod 8 -> same XCD
    const int slice = bid >> 6;        // kv slice 0..7
    const int s     = grp >> 3;
    const int hkv   = grp & 7;

    const int tid  = threadIdx.x;
    const int w    = tid >> 6;         // 0..7
    const int lane = tid & 63;
    const int l32  = lane & 31;
    const int hi2  = lane >> 5;
    const int g    = w >> 1;           // GQA sub-head
    const int qh   = w & 1;            // q-token half: [32*qh, 32*qh+32)

    unsigned char* KB = smem;
    unsigned char* VB = smem + 16384;
    unsigned char* PB = smem + 32768 + w * 2048;

    const float QSCALE = 0.08838834764831845f * 1.44269504088896340736f;

    // ---- Q -> registers (B-frag of swapped QK): Q[q=l32][d = dc*16 + hi2*8 + j]
    bf16x8 aq[8];
    {
        const float* qp =
            qg + (size_t)((s * 64 + qh * 32 + l32) * 32 + hkv * 4 + g) * 128;
#pragma unroll
        for (int dc = 0; dc < 8; ++dc) {
            const float* p = qp + dc * 16 + hi2 * 8;
            const float4 f0 = *(const float4*)(p);
            const float4 f1 = *(const float4*)(p + 4);
            uint4 tt = make_uint4(pkbf(f0.x * QSCALE, f0.y * QSCALE),
                                  pkbf(f0.z * QSCALE, f0.w * QSCALE),
                                  pkbf(f1.x * QSCALE, f1.y * QSCALE),
                                  pkbf(f1.z * QSCALE, f1.w * QSCALE));
            aq[dc] = __builtin_bit_cast(bf16x8, tt);
        }
    }

    f32x16 acco[4];
#pragma unroll
    for (int dc = 0; dc < 4; ++dc) acco[dc] = (f32x16)0.f;
    float lsum = 0.f;

    // staging: K via 2 float4/thread; V via 8 scalars/thread (d along lanes)
    const int vd  = tid & 127;         // V: d row
    const int vkg = tid >> 7;          // V: kv quad -> 16B unit

    float4 kreg[2];
    float  vreg[8];

    // 66 tiles over 8 slices: slices 0,1 take 9; slices 2..7 take 8.
    const int tile0 = slice * 8 + (slice < 2 ? slice : 2);
    const int nt    = 8 + (slice < 2 ? 1 : 0);

    auto load_regs = [&](int T) {
        const float *ks, *vs;
        if (T < 64) {
            const int blk = bt[s * 32 + (T >> 1)];
            const size_t base = (size_t)blk * 65536 + (size_t)(T & 1) * 32768 + hkv * 128;
            ks = kcache + base; vs = vcache + base;
        } else {
            const size_t base = (size_t)(s * 64 + (T & 1) * 32) * 1024 + hkv * 128;
            ks = kin + base; vs = vin + base;
        }
#pragma unroll
        for (int i = 0; i < 2; ++i) {
            const int f = tid + 512 * i;
            kreg[i] = *(const float4*)(ks + (size_t)(f >> 5) * 1024 + (f & 31) * 4);
        }
#pragma unroll
        for (int j = 0; j < 8; ++j)
            vreg[j] = vs[(size_t)(vkg * 8 + j) * 1024 + vd];
    };

    auto write_lds = [&](int buf) {
        unsigned char* K = KB + buf * 8192;
        unsigned char* V = VB + buf * 8192;
#pragma unroll
        for (int i = 0; i < 2; ++i) {
            const int f  = tid + 512 * i;
            const int kv = f >> 5;
            const int dk = f & 31;                  // 8B unit in 256B row
            const int Xs = dk ^ ((kv & 15) << 1);
            *(uint2*)(K + kv * 256 + Xs * 8) =
                make_uint2(pkbf(kreg[i].x, kreg[i].y), pkbf(kreg[i].z, kreg[i].w));
        }
        const int u = vkg ^ ((vd >> 1) & 3);        // V^T row vd: 64B, 4x16B units
        *(uint4*)(V + vd * 64 + u * 16) =
            make_uint4(pkbf(vreg[0], vreg[1]), pkbf(vreg[2], vreg[3]),
                       pkbf(vreg[4], vreg[5]), pkbf(vreg[6], vreg[7]));
    };

    const int vq = (l32 >> 1) & 3;     // P/V read swizzle for this lane

    auto compute = [&](int buf) {
        const unsigned char* K = KB + buf * 8192;
        const unsigned char* V = VB + buf * 8192;

        // swapped QK^T: C[kv][q], col q = l32
        f32x16 sc = (f32x16)0.f;
        __builtin_amdgcn_s_setprio(1);
#pragma unroll
        for (int dc = 0; dc < 8; ++dc) {
            const int u = (dc * 2 + hi2) ^ (l32 & 15);
            const bf16x8 ak = *(const bf16x8*)(K + l32 * 256 + u * 16);
            sc = __builtin_amdgcn_mfma_f32_32x32x16_bf16(ak, aq[dc], sc, 0, 0, 0);
        }
        __builtin_amdgcn_s_setprio(0);

        // lane-local no-max softmax (rows kv = (r&3) + 8*(r>>2) + 4*hi2)
        float p[16];
#pragma unroll
        for (int r = 0; r < 16; ++r) {
            p[r] = __builtin_amdgcn_exp2f(sc[r]);
            lsum += p[r];
        }

        // P -> per-wave LDS [q rows of 64B], block-XOR swizzle
#pragma unroll
        for (int rq = 0; rq < 4; ++rq)
#pragma unroll
            for (int e = 0; e < 2; ++e)
                *(unsigned*)(PB + l32 * 64 + ((rq ^ vq) * 16) + (2 * hi2 + e) * 4) =
                    pkbf(p[rq * 4 + 2 * e], p[rq * 4 + 2 * e + 1]);
        asm volatile("s_waitcnt lgkmcnt(0)" ::: "memory"); // wave-private buffer

        bf16x8 pa[2];
#pragma unroll
        for (int kk = 0; kk < 2; ++kk)
            pa[kk] = *(const bf16x8*)(PB + l32 * 64 + (((kk * 2 + hi2) ^ vq) * 16));

        // PV: C[q][d] per 32-d block
        __builtin_amdgcn_s_setprio(1);
#pragma unroll
        for (int kk = 0; kk < 2; ++kk)
#pragma unroll
            for (int d2 = 0; d2 < 4; ++d2) {
                const int u = (kk * 2 + hi2) ^ vq;
                const bf16x8 bv = *(const bf16x8*)(V + (d2 * 32 + l32) * 64 + u * 16);
                acco[d2] = __builtin_amdgcn_mfma_f32_32x32x16_bf16(pa[kk], bv, acco[d2], 0, 0, 0);
            }
        __builtin_amdgcn_s_setprio(0);
    };

    // ---- prologue + main loop: ONE barrier per tile
    load_regs(tile0);
    write_lds(0);
    load_regs(tile0 + 1);

    for (int tt = 0; tt < nt; ++tt) {
        __syncthreads();
        if (tt + 1 < nt) write_lds((tt + 1) & 1);
        if (tt + 2 < nt) load_regs(tile0 + tt + 2);
        compute(tt & 1);
    }

    // ---- epilogue: slice partials -> workspace (O as bf16, L as f32)
    const float lt = lsum + __shfl_xor(lsum, 32);   // full kv-sum for q-col l32
    const size_t gq = (size_t)(slice * 64 + grp) * 256 + w * 32;
    if (hi2 == 0) Lws[gq + l32] = lt;
    __hip_bfloat16* Od = Ows + gq * 128;
#pragma unroll
    for (int dc = 0; dc < 4; ++dc)
#pragma unroll
        for (int r = 0; r < 16; ++r) {
            const int qiw = (r & 3) + 8 * (r >> 2) + 4 * hi2;
            Od[(size_t)qiw * 128 + dc * 32 + l32] = __float2bfloat16(acco[dc][r]);
        }
}

__launch_bounds__(256)
__global__ void attn_combine(const __hip_bfloat16* __restrict__ Ows,
                             const float* __restrict__ Lws,
                             float* __restrict__ out)
{
    const int idx = blockIdx.x * 256 + threadIdx.x;  // 0..524287
    const int dq  = idx & 31;                        // 4-wide d group in d=128
    const int qr  = (idx >> 5) & 255;                // q-row in group (g*64+qtok)
    const int grp = idx >> 13;                       // 0..63
    const int s = grp >> 3, hkv = grp & 7;
    const int g = qr >> 6, qtok = qr & 63;

    float4 acc = make_float4(0.f, 0.f, 0.f, 0.f);
    float  l   = 0.f;
#pragma unroll
    for (int sl = 0; sl < 8; ++sl) {
        const size_t base = (size_t)(sl * 64 + grp) * 256 + qr;
        const ushort4 p = *(const ushort4*)(Ows + base * 128 + dq * 4);
        acc.x += bf2f(p.x); acc.y += bf2f(p.y);
        acc.z += bf2f(p.z); acc.w += bf2f(p.w);
        l += Lws[base];
    }
    const float inv = 1.0f / l;
    float4 o = make_float4(acc.x * inv, acc.y * inv, acc.z * inv, acc.w * inv);
    *(float4*)(out + ((size_t)((s * 64 + qtok) * 32 + hkv * 4 + g)) * 128 + dq * 4) = o;
}

__device__ __forceinline__ float bf2f_check_unused() { return 0.f; }

extern "C" void kernel_launch(void* const* d_in, const int* in_sizes, int n_in,
                              void* d_out, int out_size, void* d_ws, size_t ws_size,
                              hipStream_t stream)
{
    const float* q  = (const float*)d_in[0];
    const float* k  = (const float*)d_in[1];
    const float* v  = (const float*)d_in[2];
    const float* kc = (const float*)d_in[3];
    const float* vc = (const float*)d_in[4];
    const int*   bt = (const int*)d_in[5];
    __hip_bfloat16* Ows = (__hip_bfloat16*)d_ws;
    float* Lws = (float*)((char*)d_ws + (size_t)OWS_ELEMS * 2);
    float* o   = (float*)d_out;

    attn_part<<<dim3(512), dim3(512), 0, stream>>>(q, k, v, kc, vc, bt, Ows, Lws);
    attn_combine<<<dim3(2048), dim3(256), 0, stream>>>(Ows, Lws, o);
}

// Round 10
// 42.717 us; speedup vs baseline: 3.3548x; 1.2128x over previous
//
#include <hip/hip_runtime.h>
#include <hip/hip_bf16.h>

// Attention_69277822485182: paged GQA diffusion-block attention, fp32 in/out.
// S=8, H=32, H_KV=8 (G=4), D=128, Q=64, CTX=2048 -> 66 kv tiles of 32, no mask.
//
// Round 10: R6 structure (best: grid 256, 1 block/CU, 4 kv-slices, GQA-fused
// 8-wave blocks, 16-17 tiles each) + two deltas:
//  1) lgkm-only barrier in the main loop: __syncthreads() emits
//     vmcnt(0)+lgkmcnt(0) and drains the prefetch loads every tile (m97
//     structural stall). Correctness only needs LDS visibility -> inline-asm
//     "s_waitcnt lgkmcnt(0); s_barrier". Global prefetch loads stay in
//     flight across the barrier; each wave's private vmcnt wait (compiler-
//     inserted before kreg/vreg use in write_lds) is the only VMEM wait.
//  2) bf16 ws O-partials (R9-proven numerically free): halves partial
//     round-trip traffic (33.5 -> 16.8 MB each way).
//  Kept verified: single-barrier dbuf rotation {barrier; write(t+1);
//  load(t+2); compute(t)}, 32x32x16 swapped QK^T (lane-local no-max exp2
//  softmax), K/V/P conflict-free swizzles, combine kernel.
// The reference's kv-cache scatter writes blocks never referenced by
// block_tables, so only the attention output is produced.

typedef float  f32x16 __attribute__((ext_vector_type(16)));
typedef short  bf16x8 __attribute__((ext_vector_type(8)));

__device__ __forceinline__ unsigned pkbf(float lo, float hi) {
    union { __hip_bfloat162 h; unsigned u; } t;
    t.h.x = __float2bfloat16(lo);
    t.h.y = __float2bfloat16(hi);
    return t.u;
}
__device__ __forceinline__ float bf2f(unsigned short u) {
    return __uint_as_float((unsigned)u << 16);
}

// LDS-visibility-only barrier: leave global loads (vmcnt) in flight.
#define BARRIER_LGKM() asm volatile("s_waitcnt lgkmcnt(0)\n\ts_barrier" ::: "memory")

// ws layout: Ows [4][64][256][128] bf16 (16.78 MB), then Lws [4][64][256] f32.
#define OWS_ELEMS (4u * 64u * 256u * 128u)

__launch_bounds__(512, 2)
__global__ void attn_part(const float* __restrict__ qg,
                          const float* __restrict__ kin,
                          const float* __restrict__ vin,
                          const float* __restrict__ kcache,
                          const float* __restrict__ vcache,
                          const int*   __restrict__ bt,
                          __hip_bfloat16* __restrict__ Ows,
                          float* __restrict__ Lws)
{
    // K dbuf 2x8KB @0, V^T dbuf 2x8KB @16384, P 8x2KB @32768 -> 48KB
    __shared__ __align__(16) unsigned char smem[49152];

    const int bid   = blockIdx.x;
    const int grp   = bid & 63;        // (s,hkv); slice siblings == mod 8 -> same XCD
    const int slice = bid >> 6;        // kv slice 0..3
    const int s     = grp >> 3;
    const int hkv   = grp & 7;

    const int tid  = threadIdx.x;
    const int w    = tid >> 6;         // 0..7
    const int lane = tid & 63;
    const int l32  = lane & 31;
    const int hi2  = lane >> 5;
    const int g    = w >> 1;           // GQA sub-head
    const int qh   = w & 1;            // q-token half: [32*qh, 32*qh+32)

    unsigned char* KB = smem;
    unsigned char* VB = smem + 16384;
    unsigned char* PB = smem + 32768 + w * 2048;

    const float QSCALE = 0.08838834764831845f * 1.44269504088896340736f;

    // ---- Q -> registers (B-frag of swapped QK): Q[q=l32][d = dc*16 + hi2*8 + j]
    bf16x8 aq[8];
    {
        const float* qp =
            qg + (size_t)((s * 64 + qh * 32 + l32) * 32 + hkv * 4 + g) * 128;
#pragma unroll
        for (int dc = 0; dc < 8; ++dc) {
            const float* p = qp + dc * 16 + hi2 * 8;
            const float4 f0 = *(const float4*)(p);
            const float4 f1 = *(const float4*)(p + 4);
            uint4 tt = make_uint4(pkbf(f0.x * QSCALE, f0.y * QSCALE),
                                  pkbf(f0.z * QSCALE, f0.w * QSCALE),
                                  pkbf(f1.x * QSCALE, f1.y * QSCALE),
                                  pkbf(f1.z * QSCALE, f1.w * QSCALE));
            aq[dc] = __builtin_bit_cast(bf16x8, tt);
        }
    }

    f32x16 acco[4];
#pragma unroll
    for (int dc = 0; dc < 4; ++dc) acco[dc] = (f32x16)0.f;
    float lsum = 0.f;

    // staging: K via 2 float4/thread; V via 8 scalars/thread (d along lanes)
    const int vd  = tid & 127;         // V: d row
    const int vkg = tid >> 7;          // V: kv quad -> 16B unit

    float4 kreg[2];
    float  vreg[8];

    // tiles: slice 0: 0..16, 1: 17..33, 2: 34..49, 3: 50..65
    const int tile0 = (slice < 2) ? slice * 17 : 34 + (slice - 2) * 16;
    const int nt    = (slice < 2) ? 17 : 16;

    auto load_regs = [&](int T) {
        const float *ks, *vs;
        if (T < 64) {
            const int blk = bt[s * 32 + (T >> 1)];
            const size_t base = (size_t)blk * 65536 + (size_t)(T & 1) * 32768 + hkv * 128;
            ks = kcache + base; vs = vcache + base;
        } else {
            const size_t base = (size_t)(s * 64 + (T & 1) * 32) * 1024 + hkv * 128;
            ks = kin + base; vs = vin + base;
        }
#pragma unroll
        for (int i = 0; i < 2; ++i) {
            const int f = tid + 512 * i;
            kreg[i] = *(const float4*)(ks + (size_t)(f >> 5) * 1024 + (f & 31) * 4);
        }
#pragma unroll
        for (int j = 0; j < 8; ++j)
            vreg[j] = vs[(size_t)(vkg * 8 + j) * 1024 + vd];
    };

    auto write_lds = [&](int buf) {
        unsigned char* K = KB + buf * 8192;
        unsigned char* V = VB + buf * 8192;
#pragma unroll
        for (int i = 0; i < 2; ++i) {
            const int f  = tid + 512 * i;
            const int kv = f >> 5;
            const int dk = f & 31;                  // 8B unit in 256B row
            const int Xs = dk ^ ((kv & 15) << 1);
            *(uint2*)(K + kv * 256 + Xs * 8) =
                make_uint2(pkbf(kreg[i].x, kreg[i].y), pkbf(kreg[i].z, kreg[i].w));
        }
        const int u = vkg ^ ((vd >> 1) & 3);        // V^T row vd: 64B, 4x16B units
        *(uint4*)(V + vd * 64 + u * 16) =
            make_uint4(pkbf(vreg[0], vreg[1]), pkbf(vreg[2], vreg[3]),
                       pkbf(vreg[4], vreg[5]), pkbf(vreg[6], vreg[7]));
    };

    const int vq = (l32 >> 1) & 3;     // P/V read swizzle for this lane

    auto compute = [&](int buf) {
        const unsigned char* K = KB + buf * 8192;
        const unsigned char* V = VB + buf * 8192;

        // swapped QK^T: C[kv][q], col q = l32
        f32x16 sc = (f32x16)0.f;
#pragma unroll
        for (int dc = 0; dc < 8; ++dc) {
            const int u = (dc * 2 + hi2) ^ (l32 & 15);
            const bf16x8 ak = *(const bf16x8*)(K + l32 * 256 + u * 16);
            sc = __builtin_amdgcn_mfma_f32_32x32x16_bf16(ak, aq[dc], sc, 0, 0, 0);
        }

        // lane-local no-max softmax (rows kv = (r&3) + 8*(r>>2) + 4*hi2)
        float p[16];
#pragma unroll
        for (int r = 0; r < 16; ++r) {
            p[r] = __builtin_amdgcn_exp2f(sc[r]);
            lsum += p[r];
        }

        // P -> per-wave LDS [q rows of 64B], block-XOR swizzle
#pragma unroll
        for (int rq = 0; rq < 4; ++rq)
#pragma unroll
            for (int e = 0; e < 2; ++e)
                *(unsigned*)(PB + l32 * 64 + ((rq ^ vq) * 16) + (2 * hi2 + e) * 4) =
                    pkbf(p[rq * 4 + 2 * e], p[rq * 4 + 2 * e + 1]);
        asm volatile("s_waitcnt lgkmcnt(0)" ::: "memory"); // wave-private buffer

        bf16x8 pa[2];
#pragma unroll
        for (int kk = 0; kk < 2; ++kk)
            pa[kk] = *(const bf16x8*)(PB + l32 * 64 + (((kk * 2 + hi2) ^ vq) * 16));

        // PV: C[q][d] per 32-d block
#pragma unroll
        for (int kk = 0; kk < 2; ++kk)
#pragma unroll
            for (int d2 = 0; d2 < 4; ++d2) {
                const int u = (kk * 2 + hi2) ^ vq;
                const bf16x8 bv = *(const bf16x8*)(V + (d2 * 32 + l32) * 64 + u * 16);
                acco[d2] = __builtin_amdgcn_mfma_f32_32x32x16_bf16(pa[kk], bv, acco[d2], 0, 0, 0);
            }
    };

    // ---- prologue + main loop: ONE lgkm-only barrier per tile
    load_regs(tile0);
    write_lds(0);
    load_regs(tile0 + 1);

    for (int tt = 0; tt < nt; ++tt) {
        BARRIER_LGKM();                             // LDS visible; vmcnt stays in flight
        if (tt + 1 < nt) write_lds((tt + 1) & 1);   // compiler waits my vmcnt here
        if (tt + 2 < nt) load_regs(tile0 + tt + 2); // issue next loads
        compute(tt & 1);
    }

    // ---- epilogue: slice partials -> workspace (O as bf16, L as f32)
    const float lt = lsum + __shfl_xor(lsum, 32);   // full kv-sum for q-col l32
    const size_t gq = (size_t)(slice * 64 + grp) * 256 + w * 32;
    if (hi2 == 0) Lws[gq + l32] = lt;
    __hip_bfloat16* Od = Ows + gq * 128;
#pragma unroll
    for (int dc = 0; dc < 4; ++dc)
#pragma unroll
        for (int r = 0; r < 16; ++r) {
            const int qiw = (r & 3) + 8 * (r >> 2) + 4 * hi2;
            Od[(size_t)qiw * 128 + dc * 32 + l32] = __float2bfloat16(acco[dc][r]);
        }
}

__launch_bounds__(256)
__global__ void attn_combine(const __hip_bfloat16* __restrict__ Ows,
                             const float* __restrict__ Lws,
                             float* __restrict__ out)
{
    const int idx = blockIdx.x * 256 + threadIdx.x;  // 0..524287
    const int dq  = idx & 31;                        // 4-wide d group in d=128
    const int qr  = (idx >> 5) & 255;                // q-row in group (g*64+qtok)
    const int grp = idx >> 13;                       // 0..63
    const int s = grp >> 3, hkv = grp & 7;
    const int g = qr >> 6, qtok = qr & 63;

    float4 acc = make_float4(0.f, 0.f, 0.f, 0.f);
    float  l   = 0.f;
#pragma unroll
    for (int sl = 0; sl < 4; ++sl) {
        const size_t base = (size_t)(sl * 64 + grp) * 256 + qr;
        const ushort4 p = *(const ushort4*)(Ows + base * 128 + dq * 4);
        acc.x += bf2f(p.x); acc.y += bf2f(p.y);
        acc.z += bf2f(p.z); acc.w += bf2f(p.w);
        l += Lws[base];
    }
    const float inv = 1.0f / l;
    float4 o = make_float4(acc.x * inv, acc.y * inv, acc.z * inv, acc.w * inv);
    *(float4*)(out + ((size_t)((s * 64 + qtok) * 32 + hkv * 4 + g)) * 128 + dq * 4) = o;
}

extern "C" void kernel_launch(void* const* d_in, const int* in_sizes, int n_in,
                              void* d_out, int out_size, void* d_ws, size_t ws_size,
                              hipStream_t stream)
{
    const float* q  = (const float*)d_in[0];
    const float* k  = (const float*)d_in[1];
    const float* v  = (const float*)d_in[2];
    const float* kc = (const float*)d_in[3];
    const float* vc = (const float*)d_in[4];
    const int*   bt = (const int*)d_in[5];
    __hip_bfloat16* Ows = (__hip_bfloat16*)d_ws;
    float* Lws = (float*)((char*)d_ws + (size_t)OWS_ELEMS * 2);
    float* o   = (float*)d_out;

    attn_part<<<dim3(256), dim3(512), 0, stream>>>(q, k, v, kc, vc, bt, Ows, Lws);
    attn_combine<<<dim3(2048), dim3(256), 0, stream>>>(Ows, Lws, o);
}

// Round 11
// 42.252 us; speedup vs baseline: 3.3917x; 1.0110x over previous
//
#include <hip/hip_runtime.h>
#include <hip/hip_bf16.h>

// Attention_69277822485182: paged GQA diffusion-block attention, fp32 in/out.
// S=8, H=32, H_KV=8 (G=4), D=128, Q=64, CTX=2048 -> 66 kv tiles of 32, no mask.
//
// Round 11: R10 + T12 in-register P redistribution (v_permlane32_swap_b32).
//  After swapped QK^T (C[kv][q], col q=l32), lane holds P quads for
//  kv = (r&3)+8(r>>2)+4*hi2; PV A-frag needs kv = kk*16 + hi2*8 + j.
//  permlane32_swap(X,Y) swaps X's high lanes with Y's low lanes -> one swap
//  produces both needed packed words (own-low, partner-high). 8 pkbf + 4
//  swaps replace the whole P LDS round-trip (8 writes + lgkm drain + 2 reads).
//  LDS 48KB -> 32KB; QK->PV serialization removed; P values bit-identical.
//  Kept from R10 (verified): grid 256 = 64 grp x 4 kv-slices, GQA-fused
//  8-wave blocks, lgkm-only barrier + single-barrier dbuf rotation
//  {barrier; write(t+1); load(t+2); compute(t)}, 32x32x16 swapped QK^T
//  lane-local no-max exp2 softmax, K/V conflict-free swizzles, bf16 ws
//  partials + combine kernel.
// The reference's kv-cache scatter writes blocks never referenced by
// block_tables, so only the attention output is produced.

typedef float  f32x16 __attribute__((ext_vector_type(16)));
typedef short  bf16x8 __attribute__((ext_vector_type(8)));

__device__ __forceinline__ unsigned pkbf(float lo, float hi) {
    union { __hip_bfloat162 h; unsigned u; } t;
    t.h.x = __float2bfloat16(lo);
    t.h.y = __float2bfloat16(hi);
    return t.u;
}
__device__ __forceinline__ float bf2f(unsigned short u) {
    return __uint_as_float((unsigned)u << 16);
}

// LDS-visibility-only barrier: leave global loads (vmcnt) in flight.
#define BARRIER_LGKM() asm volatile("s_waitcnt lgkmcnt(0)\n\ts_barrier" ::: "memory")

// ws layout: Ows [4][64][256][128] bf16 (16.78 MB), then Lws [4][64][256] f32.
#define OWS_ELEMS (4u * 64u * 256u * 128u)

__launch_bounds__(512, 2)
__global__ void attn_part(const float* __restrict__ qg,
                          const float* __restrict__ kin,
                          const float* __restrict__ vin,
                          const float* __restrict__ kcache,
                          const float* __restrict__ vcache,
                          const int*   __restrict__ bt,
                          __hip_bfloat16* __restrict__ Ows,
                          float* __restrict__ Lws)
{
    // K dbuf 2x8KB @0, V^T dbuf 2x8KB @16384 -> 32KB
    __shared__ __align__(16) unsigned char smem[32768];

    const int bid   = blockIdx.x;
    const int grp   = bid & 63;        // (s,hkv); slice siblings == mod 8 -> same XCD
    const int slice = bid >> 6;        // kv slice 0..3
    const int s     = grp >> 3;
    const int hkv   = grp & 7;

    const int tid  = threadIdx.x;
    const int w    = tid >> 6;         // 0..7
    const int lane = tid & 63;
    const int l32  = lane & 31;
    const int hi2  = lane >> 5;
    const int g    = w >> 1;           // GQA sub-head
    const int qh   = w & 1;            // q-token half: [32*qh, 32*qh+32)

    unsigned char* KB = smem;
    unsigned char* VB = smem + 16384;

    const float QSCALE = 0.08838834764831845f * 1.44269504088896340736f;

    // ---- Q -> registers (B-frag of swapped QK): Q[q=l32][d = dc*16 + hi2*8 + j]
    bf16x8 aq[8];
    {
        const float* qp =
            qg + (size_t)((s * 64 + qh * 32 + l32) * 32 + hkv * 4 + g) * 128;
#pragma unroll
        for (int dc = 0; dc < 8; ++dc) {
            const float* p = qp + dc * 16 + hi2 * 8;
            const float4 f0 = *(const float4*)(p);
            const float4 f1 = *(const float4*)(p + 4);
            uint4 tt = make_uint4(pkbf(f0.x * QSCALE, f0.y * QSCALE),
                                  pkbf(f0.z * QSCALE, f0.w * QSCALE),
                                  pkbf(f1.x * QSCALE, f1.y * QSCALE),
                                  pkbf(f1.z * QSCALE, f1.w * QSCALE));
            aq[dc] = __builtin_bit_cast(bf16x8, tt);
        }
    }

    f32x16 acco[4];
#pragma unroll
    for (int dc = 0; dc < 4; ++dc) acco[dc] = (f32x16)0.f;
    float lsum = 0.f;

    // staging: K via 2 float4/thread; V via 8 scalars/thread (d along lanes)
    const int vd  = tid & 127;         // V: d row
    const int vkg = tid >> 7;          // V: kv quad -> 16B unit

    float4 kreg[2];
    float  vreg[8];

    // tiles: slice 0: 0..16, 1: 17..33, 2: 34..49, 3: 50..65
    const int tile0 = (slice < 2) ? slice * 17 : 34 + (slice - 2) * 16;
    const int nt    = (slice < 2) ? 17 : 16;

    auto load_regs = [&](int T) {
        const float *ks, *vs;
        if (T < 64) {
            const int blk = bt[s * 32 + (T >> 1)];
            const size_t base = (size_t)blk * 65536 + (size_t)(T & 1) * 32768 + hkv * 128;
            ks = kcache + base; vs = vcache + base;
        } else {
            const size_t base = (size_t)(s * 64 + (T & 1) * 32) * 1024 + hkv * 128;
            ks = kin + base; vs = vin + base;
        }
#pragma unroll
        for (int i = 0; i < 2; ++i) {
            const int f = tid + 512 * i;
            kreg[i] = *(const float4*)(ks + (size_t)(f >> 5) * 1024 + (f & 31) * 4);
        }
#pragma unroll
        for (int j = 0; j < 8; ++j)
            vreg[j] = vs[(size_t)(vkg * 8 + j) * 1024 + vd];
    };

    auto write_lds = [&](int buf) {
        unsigned char* K = KB + buf * 8192;
        unsigned char* V = VB + buf * 8192;
#pragma unroll
        for (int i = 0; i < 2; ++i) {
            const int f  = tid + 512 * i;
            const int kv = f >> 5;
            const int dk = f & 31;                  // 8B unit in 256B row
            const int Xs = dk ^ ((kv & 15) << 1);
            *(uint2*)(K + kv * 256 + Xs * 8) =
                make_uint2(pkbf(kreg[i].x, kreg[i].y), pkbf(kreg[i].z, kreg[i].w));
        }
        const int u = vkg ^ ((vd >> 1) & 3);        // V^T row vd: 64B, 4x16B units
        *(uint4*)(V + vd * 64 + u * 16) =
            make_uint4(pkbf(vreg[0], vreg[1]), pkbf(vreg[2], vreg[3]),
                       pkbf(vreg[4], vreg[5]), pkbf(vreg[6], vreg[7]));
    };

    const int vq = (l32 >> 1) & 3;     // V read swizzle for this lane

    auto compute = [&](int buf) {
        const unsigned char* K = KB + buf * 8192;
        const unsigned char* V = VB + buf * 8192;

        // swapped QK^T: C[kv][q], col q = l32
        f32x16 sc = (f32x16)0.f;
#pragma unroll
        for (int dc = 0; dc < 8; ++dc) {
            const int u = (dc * 2 + hi2) ^ (l32 & 15);
            const bf16x8 ak = *(const bf16x8*)(K + l32 * 256 + u * 16);
            sc = __builtin_amdgcn_mfma_f32_32x32x16_bf16(ak, aq[dc], sc, 0, 0, 0);
        }

        // lane-local no-max softmax (rows kv = (r&3) + 8*(r>>2) + 4*hi2)
        float p[16];
#pragma unroll
        for (int r = 0; r < 16; ++r) {
            p[r] = __builtin_amdgcn_exp2f(sc[r]);
            lsum += p[r];
        }

        // ---- T12: in-register P -> A-frag via permlane32_swap (no LDS).
        // quads: A=kv[4hi2+0..3], B=kv[8+4hi2+..], C=kv[16+4hi2+..], D=kv[24+..]
        unsigned A0 = pkbf(p[0],  p[1]),  A1 = pkbf(p[2],  p[3]);
        unsigned B0 = pkbf(p[4],  p[5]),  B1 = pkbf(p[6],  p[7]);
        unsigned C0 = pkbf(p[8],  p[9]),  C1 = pkbf(p[10], p[11]);
        unsigned D0 = pkbf(p[12], p[13]), D1 = pkbf(p[14], p[15]);
        // swap X's high lanes with Y's low lanes: X' = {X_lo | Y_lo@hi},
        // Y' = {X_hi@lo | Y_hi}  -> pa words [X0',X1',Y0',Y1']
        asm volatile("v_permlane32_swap_b32 %0, %1" : "+v"(A0), "+v"(B0));
        asm volatile("v_permlane32_swap_b32 %0, %1" : "+v"(A1), "+v"(B1));
        asm volatile("v_permlane32_swap_b32 %0, %1" : "+v"(C0), "+v"(D0));
        asm volatile("v_permlane32_swap_b32 %0, %1" : "+v"(C1), "+v"(D1));
        bf16x8 pa[2];
        {
            uint4 t0 = make_uint4(A0, A1, B0, B1);   // kv = hi2*8 + 0..7
            uint4 t1 = make_uint4(C0, C1, D0, D1);   // kv = 16 + hi2*8 + 0..7
            pa[0] = __builtin_bit_cast(bf16x8, t0);
            pa[1] = __builtin_bit_cast(bf16x8, t1);
        }

        // PV: C[q][d] per 32-d block
#pragma unroll
        for (int kk = 0; kk < 2; ++kk)
#pragma unroll
            for (int d2 = 0; d2 < 4; ++d2) {
                const int u = (kk * 2 + hi2) ^ vq;
                const bf16x8 bv = *(const bf16x8*)(V + (d2 * 32 + l32) * 64 + u * 16);
                acco[d2] = __builtin_amdgcn_mfma_f32_32x32x16_bf16(pa[kk], bv, acco[d2], 0, 0, 0);
            }
    };

    // ---- prologue + main loop: ONE lgkm-only barrier per tile
    load_regs(tile0);
    write_lds(0);
    load_regs(tile0 + 1);

    for (int tt = 0; tt < nt; ++tt) {
        BARRIER_LGKM();                             // LDS visible; vmcnt stays in flight
        if (tt + 1 < nt) write_lds((tt + 1) & 1);   // compiler waits my vmcnt here
        if (tt + 2 < nt) load_regs(tile0 + tt + 2); // issue next loads
        compute(tt & 1);
    }

    // ---- epilogue: slice partials -> workspace (O as bf16, L as f32)
    const float lt = lsum + __shfl_xor(lsum, 32);   // full kv-sum for q-col l32
    const size_t gq = (size_t)(slice * 64 + grp) * 256 + w * 32;
    if (hi2 == 0) Lws[gq + l32] = lt;
    __hip_bfloat16* Od = Ows + gq * 128;
#pragma unroll
    for (int dc = 0; dc < 4; ++dc)
#pragma unroll
        for (int r = 0; r < 16; ++r) {
            const int qiw = (r & 3) + 8 * (r >> 2) + 4 * hi2;
            Od[(size_t)qiw * 128 + dc * 32 + l32] = __float2bfloat16(acco[dc][r]);
        }
}

__launch_bounds__(256)
__global__ void attn_combine(const __hip_bfloat16* __restrict__ Ows,
                             const float* __restrict__ Lws,
                             float* __restrict__ out)
{
    const int idx = blockIdx.x * 256 + threadIdx.x;  // 0..524287
    const int dq  = idx & 31;                        // 4-wide d group in d=128
    const int qr  = (idx >> 5) & 255;                // q-row in group (g*64+qtok)
    const int grp = idx >> 13;                       // 0..63
    const int s = grp >> 3, hkv = grp & 7;
    const int g = qr >> 6, qtok = qr & 63;

    float4 acc = make_float4(0.f, 0.f, 0.f, 0.f);
    float  l   = 0.f;
#pragma unroll
    for (int sl = 0; sl < 4; ++sl) {
        const size_t base = (size_t)(sl * 64 + grp) * 256 + qr;
        const ushort4 p = *(const ushort4*)(Ows + base * 128 + dq * 4);
        acc.x += bf2f(p.x); acc.y += bf2f(p.y);
        acc.z += bf2f(p.z); acc.w += bf2f(p.w);
        l += Lws[base];
    }
    const float inv = 1.0f / l;
    float4 o = make_float4(acc.x * inv, acc.y * inv, acc.z * inv, acc.w * inv);
    *(float4*)(out + ((size_t)((s * 64 + qtok) * 32 + hkv * 4 + g)) * 128 + dq * 4) = o;
}

extern "C" void kernel_launch(void* const* d_in, const int* in_sizes, int n_in,
                              void* d_out, int out_size, void* d_ws, size_t ws_size,
                              hipStream_t stream)
{
    const float* q  = (const float*)d_in[0];
    const float* k  = (const float*)d_in[1];
    const float* v  = (const float*)d_in[2];
    const float* kc = (const float*)d_in[3];
    const float* vc = (const float*)d_in[4];
    const int*   bt = (const int*)d_in[5];
    __hip_bfloat16* Ows = (__hip_bfloat16*)d_ws;
    float* Lws = (float*)((char*)d_ws + (size_t)OWS_ELEMS * 2);
    float* o   = (float*)d_out;

    attn_part<<<dim3(256), dim3(512), 0, stream>>>(q, k, v, kc, vc, bt, Ows, Lws);
    attn_combine<<<dim3(2048), dim3(256), 0, stream>>>(Ows, Lws, o);
}